// Round 11
// baseline (261.533 us; speedup 1.0000x reference)
//
#include <hip/hip_runtime.h>

// ---------------- constants ----------------
#define SS    4096
#define HH    2048
#define NQQ   18
#define QH    72
#define SCALE_F 0.044194173824159216f   // 1/sqrt(512)

// output regions (f32 elements)
#define OUT_MEM     0
#define OUT_PRI     131072
#define OUT_CONF    131136
#define OUT_VAL     131140
#define OUT_ENT     131144
#define OUT_NEWPRI  393288

typedef float  f32x4  __attribute__((ext_vector_type(4)));
typedef __bf16 bf16x8 __attribute__((ext_vector_type(8)));
typedef __bf16 bf16x4 __attribute__((ext_vector_type(4)));

#define DEVFN static __device__ __forceinline__

DEVFN bf16x8 pack8(f32x4 lo, f32x4 hi){
  bf16x8 r;
  #pragma unroll
  for (int i = 0; i < 4; i++){ r[i] = (__bf16)lo[i]; r[i+4] = (__bf16)hi[i]; }
  return r;
}
DEVFN bf16x8 zero8(){
  uint4 u = {0u, 0u, 0u, 0u};
  return __builtin_bit_cast(bf16x8, u);
}
DEVFN bf16x4 cvt4(f32x4 v){
  bf16x4 r;
  #pragma unroll
  for (int i = 0; i < 4; i++) r[i] = (__bf16)v[i];
  return r;
}
DEVFN float siluf(float x){ return x / (1.f + expf(-x)); }
DEVFN float block_sum(float v, float* sb){   // 256 threads
  #pragma unroll
  for (int o = 32; o > 0; o >>= 1) v += __shfl_xor(v, o);
  int wid = threadIdx.x >> 6, lane = threadIdx.x & 63;
  if (lane == 0) sb[wid] = v;
  __syncthreads();
  v = sb[0] + sb[1] + sb[2] + sb[3];
  __syncthreads();
  return v;
}

// ======== GEMM-BT body: Cp[y][Mp][N] = A_bf16(Mp,Kf) @ B_f32(N,Kf)^T ========
template<int MF, int KC, bool HSEL>
DEVFN void gemm_bt_body(int bx, int by, bool zsel,
    const __bf16* __restrict__ A, int Kf,
    const float* __restrict__ B0, float* __restrict__ C0,
    const float* __restrict__ B1, float* __restrict__ C1,
    int N)
{
  constexpr int Mp = 16 * MF;
  const int lane = threadIdx.x & 63, w = threadIdx.x >> 6;
  const int n0 = bx * 64 + w * 16;
  const int k0 = by * KC * 32;
  const float* B = zsel ? B1 : B0;
  float* Cp      = zsel ? C1 : C0;
  const __bf16* aBase = A + (HSEL ? (long)(n0 >> 9) * Mp * Kf : 0)
                          + (long)(lane & 15) * Kf + k0 + 8 * (lane >> 4);
  const float* bBase = B + (long)(n0 + (lane & 15)) * Kf + k0 + 8 * (lane >> 4);
  f32x4 acc[MF];
  #pragma unroll
  for (int m = 0; m < MF; m++) acc[m] = (f32x4)(0.f);
  #pragma unroll 4
  for (int c = 0; c < KC; c++){
    f32x4 lo = *reinterpret_cast<const f32x4*>(bBase + c * 32);
    f32x4 hi = *reinterpret_cast<const f32x4*>(bBase + c * 32 + 4);
    bf16x8 bb = pack8(lo, hi);
    #pragma unroll
    for (int m = 0; m < MF; m++){
      bf16x8 aa = *reinterpret_cast<const bf16x8*>(aBase + (long)m * 16 * Kf + c * 32);
      acc[m] = __builtin_amdgcn_mfma_f32_16x16x32_bf16(aa, bb, acc[m], 0, 0, 0);
    }
  }
  float* cp = Cp + (long)by * Mp * N;
  int row0 = 4 * (lane >> 4), col = n0 + (lane & 15);
  #pragma unroll
  for (int m = 0; m < MF; m++)
    #pragma unroll
    for (int r = 0; r < 4; r++)
      cp[(long)(m * 16 + row0 + r) * N + col] = acc[m][r];
}

// ======== GEMM-WK: wave-K-split GEMM, 512 threads (8 waves), no slabs ========
// C[Mp][2048] = A(Mp,2048) @ B(2048,2048); each wave reduces K=256, LDS combine.
// grid 128 (16 output cols per block). AMODE: 0=queries f32 (r<18, xSCALE)
// 1=q f32 head-masked (valid iff r<72 && r/18 == kblk(wave)); 2=bf16 direct;
// 3=bf16 HSEL (A + (n0>>9)*Mp*2048). BNAT: B strided [k][n]; else BT [n][k].
template<int MF, int AMODE, bool BNAT, bool OUTBF>
__global__ __launch_bounds__(512) void gemm_wk(
    const void* __restrict__ Ap, const float* __restrict__ B, void* __restrict__ Cv)
{
  const int lane = threadIdx.x & 63, w = threadIdx.x >> 6;   // w in 0..7
  const int n0 = blockIdx.x * 16;
  const int kw = w * 256;
  const int koff = kw + 8 * (lane >> 4);
  const int kblk = kw >> 9;
  __shared__ f32x4 red[8][MF][64];
  f32x4 acc[MF];
  #pragma unroll
  for (int m = 0; m < MF; m++) acc[m] = (f32x4)(0.f);
  int rr[MF];
  #pragma unroll
  for (int m = 0; m < MF; m++) rr[m] = (lane & 15) + 16 * m;

  const float* Bt = B + (BNAT ? ((long)koff * 2048 + n0 + (lane & 15))
                              : ((long)(n0 + (lane & 15)) * 2048 + koff));
  #pragma unroll 2
  for (int c = 0; c < 8; c++){                               // 8 * 32 = 256 K per wave
    bf16x8 bb;
    if constexpr (BNAT){
      const float* bp = Bt + (long)c * 32 * 2048;
      #pragma unroll
      for (int j = 0; j < 8; j++) bb[j] = (__bf16)bp[(long)j * 2048];
    } else {
      f32x4 lo = *reinterpret_cast<const f32x4*>(Bt + c * 32);
      f32x4 hi = *reinterpret_cast<const f32x4*>(Bt + c * 32 + 4);
      bb = pack8(lo, hi);
    }
    #pragma unroll
    for (int m = 0; m < MF; m++){
      bf16x8 aa;
      if constexpr (AMODE == 0){            // queries f32, pad rows >=18, fold scale
        if (rr[m] < NQQ){
          const float* ap = (const float*)Ap + (long)rr[m] * 2048 + koff + c * 32;
          f32x4 lo = *reinterpret_cast<const f32x4*>(ap);
          f32x4 hi = *reinterpret_cast<const f32x4*>(ap + 4);
          #pragma unroll
          for (int i = 0; i < 4; i++){ aa[i] = (__bf16)(lo[i]*SCALE_F); aa[i+4] = (__bf16)(hi[i]*SCALE_F); }
        } else aa = zero8();
      } else if constexpr (AMODE == 1){     // q f32 head-masked
        int h = rr[m] / NQQ;
        if (rr[m] < QH && h == kblk){
          const float* ap = (const float*)Ap + (long)(rr[m] - NQQ * h) * 2048 + koff + c * 32;
          f32x4 lo = *reinterpret_cast<const f32x4*>(ap);
          f32x4 hi = *reinterpret_cast<const f32x4*>(ap + 4);
          aa = pack8(lo, hi);
        } else aa = zero8();
      } else if constexpr (AMODE == 2){     // bf16 direct
        aa = *reinterpret_cast<const bf16x8*>((const __bf16*)Ap + (long)rr[m] * 2048 + koff + c * 32);
      } else {                              // bf16 HSEL by output head
        aa = *reinterpret_cast<const bf16x8*>((const __bf16*)Ap
              + ((long)(n0 >> 9) * MF * 16 + rr[m]) * 2048 + koff + c * 32);
      }
      acc[m] = __builtin_amdgcn_mfma_f32_16x16x32_bf16(aa, bb, acc[m], 0, 0, 0);
    }
  }
  #pragma unroll
  for (int m = 0; m < MF; m++) red[w][m][lane] = acc[m];
  __syncthreads();
  if (w == 0){
    #pragma unroll
    for (int m = 0; m < MF; m++){
      f32x4 s = ((red[0][m][lane] + red[1][m][lane]) + (red[2][m][lane] + red[3][m][lane]))
              + ((red[4][m][lane] + red[5][m][lane]) + (red[6][m][lane] + red[7][m][lane]));
      int row0 = m * 16 + 4 * (lane >> 4), col = n0 + (lane & 15);
      #pragma unroll
      for (int j = 0; j < 4; j++){
        if constexpr (OUTBF) ((__bf16*)Cv)[(long)(row0 + j) * 2048 + col] = (__bf16)s[j];
        else                 ((float*)Cv)[(long)(row0 + j) * 2048 + col] = s[j];
      }
    }
  }
}

// ======== GEMM-ABNAT (scalar-strided B): Cp[z][y][Mp][N] = A_bf16(z) @ Bn_f32(z)(K,N) ========
// cBatch MUST equal gridDim.y * Mp * N (z-major slab layout [z][y][Mp][N]).
template<int MF, int KC>
__global__ __launch_bounds__(256) void gemm_abnat(
    const __bf16* __restrict__ A, long aBatch, int aStride,
    const float* __restrict__ Bn, long bBatch,
    float* __restrict__ Cp, long cBatch,
    int N)
{
  constexpr int Mp = 16 * MF;
  const int lane = threadIdx.x & 63, w = threadIdx.x >> 6;
  const int z = blockIdx.z;
  const int n0 = blockIdx.x * 64 + w * 16;
  const int k0 = blockIdx.y * KC * 32;
  const __bf16* aBase = A + z * aBatch + (long)(lane & 15) * aStride + k0 + 8 * (lane >> 4);
  const float* bBase = Bn + z * bBatch + (long)(k0 + 8 * (lane >> 4)) * N + n0 + (lane & 15);
  f32x4 acc[MF];
  #pragma unroll
  for (int m = 0; m < MF; m++) acc[m] = (f32x4)(0.f);
  #pragma unroll 2
  for (int c = 0; c < KC; c++){
    const float* bp = bBase + (long)c * 32 * N;
    bf16x8 bb;
    #pragma unroll
    for (int j = 0; j < 8; j++) bb[j] = (__bf16)bp[(long)j * N];
    #pragma unroll
    for (int m = 0; m < MF; m++){
      bf16x8 aa = *reinterpret_cast<const bf16x8*>(aBase + (long)m * 16 * aStride + c * 32);
      acc[m] = __builtin_amdgcn_mfma_f32_16x16x32_bf16(aa, bb, acc[m], 0, 0, 0);
    }
  }
  float* cp = Cp + z * cBatch + (long)blockIdx.y * Mp * N;
  int row0 = 4 * (lane >> 4), col = n0 + (lane & 15);
  #pragma unroll
  for (int m = 0; m < MF; m++)
    #pragma unroll
    for (int r = 0; r < 4; r++)
      cp[(long)(m * 16 + row0 + r) * N + col] = acc[m][r];
}

// ======== pass1: Sp[y][b][qh][s] = hs(b)(s,H) @ qk_bf16(80,H)^T  (y=4, KC=16) ========
template<int KC>
__global__ __launch_bounds__(256) void gemm_pass1(
    const float* __restrict__ hs, const __bf16* __restrict__ qk,
    float* __restrict__ Sp)
{
  const int lane = threadIdx.x & 63, w = threadIdx.x >> 6;
  const int b = blockIdx.z;
  const int s0 = blockIdx.x * 64 + w * 16;
  const int k0 = blockIdx.y * KC * 32;
  const float* aBase = hs + ((long)b * SS + s0 + (lane & 15)) * HH + k0 + 8 * (lane >> 4);
  const __bf16* bBase = qk + (long)(lane & 15) * HH + k0 + 8 * (lane >> 4);
  f32x4 acc[5];
  #pragma unroll
  for (int n = 0; n < 5; n++) acc[n] = (f32x4)(0.f);
  #pragma unroll 4
  for (int c = 0; c < KC; c++){
    f32x4 lo = *reinterpret_cast<const f32x4*>(aBase + c * 32);
    f32x4 hi = *reinterpret_cast<const f32x4*>(aBase + c * 32 + 4);
    bf16x8 aa = pack8(lo, hi);
    #pragma unroll
    for (int n = 0; n < 5; n++){
      bf16x8 bb = *reinterpret_cast<const bf16x8*>(bBase + (long)n * 16 * HH + c * 32);
      acc[n] = __builtin_amdgcn_mfma_f32_16x16x32_bf16(aa, bb, acc[n], 0, 0, 0);
    }
  }
  float* sp = Sp + ((long)blockIdx.y * 4 + b) * 80 * SS;
  int scol = s0 + 4 * (lane >> 4);
  #pragma unroll
  for (int n = 0; n < 5; n++){
    int qh = n * 16 + (lane & 15);
    *reinterpret_cast<f32x4*>(sp + (long)qh * SS + scol) = acc[n];
  }
}

// ======== merged FFN launches (independent GEMMs by block range, no sync) ========
__global__ __launch_bounds__(256) void k_ffn1(
    const __bf16* __restrict__ xnb, const float* __restrict__ Wgate, const float* __restrict__ Wup,
    float* __restrict__ gate_p, float* __restrict__ up_p,
    const __bf16* __restrict__ vi, const float* __restrict__ V1, float* __restrict__ h1_p)
{
  int bid = blockIdx.x;
  if (bid < 1024){                                   // gate/up: (64,8,2), KC=8, 8 slabs
    int z = bid >> 9, rem = bid & 511;
    gemm_bt_body<4, 8, false>(rem & 63, rem >> 6, z != 0, xnb, 2048, Wgate, gate_p, Wup, up_p, 4096);
  } else {                                           // V1: (32,16), KC=8, 16 slabs
    int t = bid - 1024;
    gemm_bt_body<1, 8, false>(t & 31, t >> 5, false, vi, 4096, V1, h1_p, V1, h1_p, 2048);
  }
}
__global__ __launch_bounds__(256) void k_ffn2(
    const __bf16* __restrict__ hb, const float* __restrict__ Wdown, float* __restrict__ ffn_p,
    const __bf16* __restrict__ h1s, const float* __restrict__ V2, float* __restrict__ h2_p)
{
  int bid = blockIdx.x;
  if (bid < 512){                                    // down: (32,16), KC=8, 16 slabs
    gemm_bt_body<4, 8, false>(bid & 31, bid >> 5, false, hb, 4096, Wdown, ffn_p, Wdown, ffn_p, 2048);
  } else {                                           // V2: (8,16), KC=4, 16 slabs
    int t = bid - 512;
    gemm_bt_body<1, 4, false>(t & 7, t >> 3, false, h1s, 2048, V2, h2_p, V2, h2_p, 512);
  }
}
// act (256 blocks, 8 slabs, vectorized) + h1act (32 blocks, 16 slabs, vectorized)
__global__ void k_act2(const float* __restrict__ gate_p, const float* __restrict__ up_p,
                       __bf16* __restrict__ hb,
                       const float* __restrict__ h1_p, const float* __restrict__ b1,
                       __bf16* __restrict__ h1s)
{
  int bid = blockIdx.x;
  if (bid < 256){                                    // 64*4096 elems, quads
    long i = ((long)bid * 256 + threadIdx.x) * 4;
    f32x4 g = (f32x4)(0.f), u = (f32x4)(0.f);
    #pragma unroll
    for (int y = 0; y < 8; y++){
      g += *reinterpret_cast<const f32x4*>(gate_p + (long)y * 64 * 4096 + i);
      u += *reinterpret_cast<const f32x4*>(up_p   + (long)y * 64 * 4096 + i);
    }
    f32x4 o;
    #pragma unroll
    for (int j = 0; j < 4; j++) o[j] = siluf(g[j]) * u[j];
    *reinterpret_cast<bf16x4*>(hb + i) = cvt4(o);
  } else {                                           // h1act: 16*2048 elems, quads
    int i = ((bid - 256) * 256 + threadIdx.x) * 4;
    int r = i >> 11, e = i & 2047;
    f32x4 v = (f32x4)(0.f);
    if (r < 4){
      f32x4 s = (f32x4)(0.f);
      #pragma unroll
      for (int y = 0; y < 16; y++) s += *reinterpret_cast<const f32x4*>(h1_p + (long)y * 16 * 2048 + i);
      #pragma unroll
      for (int j = 0; j < 4; j++) v[j] = siluf(s[j] + b1[e + j]);
    }
    *reinterpret_cast<bf16x4*>(h1s + i) = cvt4(v);
  }
}

// ---------------- small / epilogue kernels (vectorized) ----------------
__global__ __launch_bounds__(256) void k_softmax(const float* __restrict__ Sp, __bf16* __restrict__ attn){
  int qh = blockIdx.x, b = blockIdx.y;
  __bf16* arow = attn + ((long)b * 80 + qh) * SS;
  if (qh >= QH){
    #pragma unroll
    for (int it = 0; it < 4; it++)
      *reinterpret_cast<bf16x4*>(arow + (threadIdx.x + it * 256) * 4) = cvt4((f32x4)(0.f));
    return;
  }
  const float* r0 = Sp + ((long)b * 80 + qh) * SS;
  const long ys = (long)4 * 80 * SS;
  f32x4 x4[4]; float mx = -1e30f;
  #pragma unroll
  for (int it = 0; it < 4; it++){
    int s = (threadIdx.x + it * 256) * 4;
    f32x4 a = (*reinterpret_cast<const f32x4*>(r0 + s) + *reinterpret_cast<const f32x4*>(r0 + s + ys))
            + (*reinterpret_cast<const f32x4*>(r0 + s + 2 * ys) + *reinterpret_cast<const f32x4*>(r0 + s + 3 * ys));
    x4[it] = a;
    #pragma unroll
    for (int j = 0; j < 4; j++) mx = fmaxf(mx, a[j]);
  }
  __shared__ float sb[8];
  #pragma unroll
  for (int o = 32; o > 0; o >>= 1) mx = fmaxf(mx, __shfl_xor(mx, o));
  int wid = threadIdx.x >> 6, lane = threadIdx.x & 63;
  if (lane == 0) sb[wid] = mx;
  __syncthreads();
  mx = fmaxf(fmaxf(sb[0], sb[1]), fmaxf(sb[2], sb[3]));
  float sum = 0.f;
  #pragma unroll
  for (int it = 0; it < 4; it++)
    #pragma unroll
    for (int j = 0; j < 4; j++){ x4[it][j] = expf(x4[it][j] - mx); sum += x4[it][j]; }
  #pragma unroll
  for (int o = 32; o > 0; o >>= 1) sum += __shfl_xor(sum, o);
  if (lane == 0) sb[4 + wid] = sum;
  __syncthreads();
  sum = sb[4] + sb[5] + sb[6] + sb[7];
  float inv = 1.f / sum;
  #pragma unroll
  for (int it = 0; it < 4; it++){
    int s = (threadIdx.x + it * 256) * 4;
    *reinterpret_cast<bf16x4*>(arow + s) = cvt4(x4[it] * inv);
  }
}
// w_p layout [b][y][80][2048], y in [0,8)
__global__ void k_pack_wv(const float* __restrict__ w_p, __bf16* __restrict__ Apack){
  long i = ((long)blockIdx.x * 256 + threadIdx.x) * 4;  // 4*80*2048 elems, grid 640
  int h = (int)(i / (80 * 2048));
  int r = (int)((i / 2048) % 80);
  int e = (int)(i & 2047);
  f32x4 v = (f32x4)(0.f);
  if (r < QH){
    int b = r / NQQ, qq = r - b * NQQ;
    const float* base = w_p + ((long)b * 8 * 80 + (h * NQQ + qq)) * 2048 + e;
    #pragma unroll
    for (int y = 0; y < 8; y++) v += *reinterpret_cast<const f32x4*>(base + (long)y * 80 * 2048);
  }
  *reinterpret_cast<bf16x4*>(Apack + i) = cvt4(v);
}
// rms + vi packing fused. grid 96. extracted read directly (no slabs).
__global__ __launch_bounds__(256) void k_rms(const float* __restrict__ extracted, const float* __restrict__ ln_w,
                                             const float* __restrict__ hs,
                                             __bf16* __restrict__ xnb, __bf16* __restrict__ vi){
  int r = blockIdx.x;
  int tid = threadIdx.x;
  if (r >= 80){
    if (r < 84){                                 // vi[b][2048..4096] = hs[b, S-1, :]
      int b = r - 80;
      const float* src = hs + ((long)b * SS + (SS - 1)) * HH;
      #pragma unroll
      for (int it = 0; it < 2; it++){
        int e = (tid + it * 256) * 4;
        *reinterpret_cast<bf16x4*>(vi + (long)b * 4096 + 2048 + e) =
            cvt4(*reinterpret_cast<const f32x4*>(src + e));
      }
    } else {                                     // zero vi rows 4..15
      int row = 4 + (r - 84);
      #pragma unroll
      for (int it = 0; it < 4; it++)
        *reinterpret_cast<bf16x4*>(vi + (long)row * 4096 + (tid + it * 256) * 4) = cvt4((f32x4)(0.f));
    }
    return;
  }
  f32x4 xv4[2]; float ss = 0.f;
  #pragma unroll
  for (int it = 0; it < 2; it++){
    int e = (tid + it * 256) * 4;
    f32x4 s = *reinterpret_cast<const f32x4*>(extracted + (long)r * 2048 + e);
    xv4[it] = s;
    ss += (s[0] * s[0] + s[1] * s[1]) + (s[2] * s[2] + s[3] * s[3]);
  }
  if (r >= QH) return;
  int b = r / NQQ, qq = r - b * NQQ;
  if (qq < 16){
    __shared__ float sb[4];
    ss = block_sum(ss, sb);
    float inv = 1.f / sqrtf(ss * (1.f / 2048.f) + 1e-6f);
    __bf16* dst = xnb + (long)(b * 16 + qq) * HH;
    #pragma unroll
    for (int it = 0; it < 2; it++){
      int e = (tid + it * 256) * 4;
      f32x4 lw = *reinterpret_cast<const f32x4*>(ln_w + e);
      *reinterpret_cast<bf16x4*>(dst + e) = cvt4(xv4[it] * inv * lw);
    }
  } else if (qq == 17){                          // vi[b][0..2048] = extracted row
    #pragma unroll
    for (int it = 0; it < 2; it++){
      int e = (tid + it * 256) * 4;
      *reinterpret_cast<bf16x4*>(vi + (long)b * 4096 + e) = cvt4(xv4[it]);
    }
  }
}
// memory + priority + confidence + value, one kernel. grid 72. (16 ffn slabs, 16 h2 slabs)
__global__ __launch_bounds__(256) void k_epilogue(
    const float* __restrict__ extracted, const float* __restrict__ ffn_p,
    const float* __restrict__ h2_p,
    const float* __restrict__ Wp, const float* __restrict__ bp,
    const float* __restrict__ Wh, const float* __restrict__ bh,
    const float* __restrict__ b2, const float* __restrict__ V3, const float* __restrict__ b3,
    float* __restrict__ out)
{
  __shared__ float sb[4];
  int blk = blockIdx.x, tid = threadIdx.x;
  if (blk < 64){                                 // memory row + priority
    int b = blk >> 4, qq = blk & 15;
    const float* ext = extracted + (long)(b * NQQ + qq) * HH;
    float pv = 0.f;
    #pragma unroll
    for (int it = 0; it < 2; it++){
      int e = (tid + it * 256) * 4;
      f32x4 f = (f32x4)(0.f);
      #pragma unroll
      for (int y = 0; y < 16; y++) f += *reinterpret_cast<const f32x4*>(ffn_p + ((long)y * 64 + blk) * 2048 + e);
      f32x4 m = *reinterpret_cast<const f32x4*>(ext + e) + f;
      *reinterpret_cast<f32x4*>(out + OUT_MEM + (long)blk * 2048 + e) = m;
      f32x4 wp = *reinterpret_cast<const f32x4*>(Wp + e);
      pv += (m[0] * wp[0] + m[1] * wp[1]) + (m[2] * wp[2] + m[3] * wp[3]);
    }
    pv = block_sum(pv, sb);
    if (tid == 0) out[OUT_PRI + blk] = 1.f / (1.f + expf(-(pv + bp[0])));
  } else if (blk < 68){                          // confidence
    int b = blk - 64;
    const float* m = extracted + (long)(b * NQQ + 16) * HH;
    float v = 0.f;
    #pragma unroll
    for (int it = 0; it < 2; it++){
      int e = (tid + it * 256) * 4;
      f32x4 mv = *reinterpret_cast<const f32x4*>(m + e);
      f32x4 wh = *reinterpret_cast<const f32x4*>(Wh + e);
      v += (mv[0] * wh[0] + mv[1] * wh[1]) + (mv[2] * wh[2] + mv[3] * wh[3]);
    }
    v = block_sum(v, sb);
    if (tid == 0) out[OUT_CONF + b] = 1.f / (1.f + expf(-(v + bh[0])));
  } else {                                       // value
    int b = blk - 68;
    float v = 0.f;
    if (tid < 128){
      int j = tid * 4;
      f32x4 s = (f32x4)(0.f);
      #pragma unroll
      for (int y = 0; y < 16; y++) s += *reinterpret_cast<const f32x4*>(h2_p + (long)y * 16 * 512 + b * 512 + j);
      #pragma unroll
      for (int jj = 0; jj < 4; jj++) v += siluf(s[jj] + b2[j + jj]) * V3[j + jj];
    }
    v = block_sum(v, sb);
    if (tid == 0) out[OUT_VAL + b] = v + b3[0];
  }
}
// block-redundant scan + entry copy (128 blocks)
__global__ void k_scanentries(const float* __restrict__ buf_pri, const float* __restrict__ buf_ent,
                              float* __restrict__ out){
  __shared__ int tws;
  int bid = blockIdx.x, tid = threadIdx.x;
  if (tid < 64){
    int lane = tid;
    float pr0 = buf_pri[lane], pr1 = buf_pri[lane + 64];
    int tw0 = -1, tw1 = -1;
    for (int i = 0; i < 16; i++){
      float pp = out[OUT_PRI + i];
      float v; int idx;
      if (pr0 <= pr1){ v = pr0; idx = lane; } else { v = pr1; idx = lane + 64; }
      #pragma unroll
      for (int o = 32; o > 0; o >>= 1){
        float ov = __shfl_xor(v, o);
        int   oi = __shfl_xor(idx, o);
        if (ov < v || (ov == v && oi < idx)){ v = ov; idx = oi; }
      }
      if (pp > v){
        if (idx == lane)          { pr0 = pp; tw0 = i; }
        else if (idx == lane + 64){ pr1 = pp; tw1 = i; }
      }
    }
    if (bid == 0){
      out[OUT_NEWPRI + lane]      = pr0;
      out[OUT_NEWPRI + lane + 64] = pr1;
    }
    if (lane == (bid & 63)) tws = (bid < 64) ? tw0 : tw1;
  }
  __syncthreads();
  int t = tws;
  const f32x4* s = reinterpret_cast<const f32x4*>(
      (t < 0) ? (buf_ent + (long)bid * HH) : (out + OUT_MEM + (long)t * HH));
  f32x4* d = reinterpret_cast<f32x4*>(out + OUT_ENT + (long)bid * HH);
  #pragma unroll
  for (int i = 0; i < 2; i++) d[tid + 256 * i] = s[tid + 256 * i];
}

// ---------------- launcher ----------------
extern "C" void kernel_launch(void* const* d_in, const int* in_sizes, int n_in,
                              void* d_out, int out_size, void* d_ws, size_t ws_size,
                              hipStream_t stream)
{
  const float* hs      = (const float*)d_in[0];
  const float* buf_ent = (const float*)d_in[1];
  const float* buf_pri = (const float*)d_in[2];
  const float* queries = (const float*)d_in[3];
  const float* Wq  = (const float*)d_in[4];
  const float* Wk  = (const float*)d_in[5];
  const float* Wv  = (const float*)d_in[6];
  const float* Wo  = (const float*)d_in[7];
  const float* ln_w= (const float*)d_in[8];
  const float* Wgate=(const float*)d_in[9];
  const float* Wup = (const float*)d_in[10];
  const float* Wdown=(const float*)d_in[11];
  const float* Wp  = (const float*)d_in[12];
  const float* bp  = (const float*)d_in[13];
  const float* Wh  = (const float*)d_in[14];
  const float* bh  = (const float*)d_in[15];
  const float* V1  = (const float*)d_in[16];
  const float* b1  = (const float*)d_in[17];
  const float* V2  = (const float*)d_in[18];
  const float* b2  = (const float*)d_in[19];
  const float* V3  = (const float*)d_in[20];
  const float* b3  = (const float*)d_in[21];
  float* out = (float*)d_out;
  char* ws = (char*)d_ws;

  // ---- RegionA (time-aliased at ws+0; lifetimes strictly serial) ----
  float* scores_p = (float*)(ws + 0);            // [4][4][80][4096]
  float* w_p      = (float*)(ws + 0);            // [4][8][80][2048]
  float* gate_p   = (float*)(ws + 0);            // [8][64][4096]
  float* up_p     = (float*)(ws + 8388608);      // [8][64][4096]
  float* ffn_p    = (float*)(ws + 0);            // [16][64][2048]
  // ---- persistents (from 20,971,520) ----
  __bf16* qk_bf = (__bf16*)(ws + 21430272);      // 80*2048
  __bf16* attn  = (__bf16*)(ws + 21757952);      // 4*80*4096
  __bf16* Apack = (__bf16*)(ws + 24379392);      // 4*80*2048
  __bf16* outB  = (__bf16*)(ws + 25690112);      // 80*2048
  float*  extracted = (float*)(ws + 26017792);   // 80*2048 f32
  __bf16* xnb   = (__bf16*)(ws + 26673152);      // 64*2048
  __bf16* hb    = (__bf16*)(ws + 26935296);      // 64*4096
  __bf16* vi    = (__bf16*)(ws + 27459584);      // 16*4096
  __bf16* h1s   = (__bf16*)(ws + 27590656);      // 16*2048
  float*  h1_p  = (float*)(ws + 27656192);       // [16][16][2048]
  float*  h2_p  = (float*)(ws + 29753344);       // [16][16][512]
  float*  q     = (float*)(ws + 30277632);       // [32][2048] f32

  // q = scale*(queries @ Wq^T), wave-K-split, direct f32 out (no slabs)
  gemm_wk<2, 0, false, false><<<128, 512, 0, stream>>>(queries, Wq, q);
  // qk_bf = mask(q) @ Wk, head-mask folded into A-load, direct bf16 out
  gemm_wk<5, 1, true, true><<<128, 512, 0, stream>>>(q, Wk, qk_bf);
  // pass1: scores_t[y][b][qh][s] = hs @ qk^T, 4 slabs
  gemm_pass1<16><<<dim3(64, 4, 4), 256, 0, stream>>>(hs, qk_bf, scores_p);
  k_softmax<<<dim3(80, 4), 256, 0, stream>>>(scores_p, attn);
  // pass3: weighted = attn @ hs, 8 slabs; w_p [b][8][80][2048]
  gemm_abnat<5, 16><<<dim3(32, 8, 4), 256, 0, stream>>>(attn, 80L * 4096, 4096,
      hs, (long)SS * HH, w_p, 8L * 80 * 2048, 2048);
  k_pack_wv<<<640, 256, 0, stream>>>(w_p, Apack);
  // V projection (block-diag by head), wave-K-split, direct bf16 out
  gemm_wk<5, 3, false, true><<<128, 512, 0, stream>>>(Apack, Wv, outB);
  // O projection, wave-K-split, direct f32 out -> extracted
  gemm_wk<5, 2, false, false><<<128, 512, 0, stream>>>(outB, Wo, extracted);
  k_rms<<<96, 256, 0, stream>>>(extracted, ln_w, hs, xnb, vi);
  // FFN up+gate (8 slabs) + value-MLP layer 1 (16 slabs), merged launch
  k_ffn1<<<1536, 256, 0, stream>>>(xnb, Wgate, Wup, gate_p, up_p, vi, V1, h1_p);
  k_act2<<<288, 256, 0, stream>>>(gate_p, up_p, hb, h1_p, b1, h1s);
  // FFN down (16 slabs) + value-MLP layer 2 (16 slabs), merged launch
  k_ffn2<<<640, 256, 0, stream>>>(hb, Wdown, ffn_p, h1s, V2, h2_p);
  // outputs
  k_epilogue<<<72, 256, 0, stream>>>(extracted, ffn_p, h2_p, Wp, bp, Wh, bh, b2, V3, b3, out);
  k_scanentries<<<128, 256, 0, stream>>>(buf_pri, buf_ent, out);
}

// Round 12
// 254.542 us; speedup vs baseline: 1.0275x; 1.0275x over previous
//
#include <hip/hip_runtime.h>

// ---------------- constants ----------------
#define SS    4096
#define HH    2048
#define NQQ   18
#define QH    72
#define SCALE_F 0.044194173824159216f   // 1/sqrt(512)

// output regions (f32 elements)
#define OUT_MEM     0
#define OUT_PRI     131072
#define OUT_CONF    131136
#define OUT_VAL     131140
#define OUT_ENT     131144
#define OUT_NEWPRI  393288

typedef float  f32x4  __attribute__((ext_vector_type(4)));
typedef __bf16 bf16x8 __attribute__((ext_vector_type(8)));

#define DEVFN static __device__ __forceinline__

DEVFN bf16x8 pack8(f32x4 lo, f32x4 hi){
  bf16x8 r;
  #pragma unroll
  for (int i = 0; i < 4; i++){ r[i] = (__bf16)lo[i]; r[i+4] = (__bf16)hi[i]; }
  return r;
}
DEVFN float siluf(float x){ return x / (1.f + expf(-x)); }
DEVFN float block_sum(float v, float* sb){   // 256 threads
  #pragma unroll
  for (int o = 32; o > 0; o >>= 1) v += __shfl_xor(v, o);
  int wid = threadIdx.x >> 6, lane = threadIdx.x & 63;
  if (lane == 0) sb[wid] = v;
  __syncthreads();
  v = sb[0] + sb[1] + sb[2] + sb[3];
  __syncthreads();
  return v;
}

// ======== GEMM-BT body: Cp[y][Mp][N] = A_bf16(Mp,Kf) @ B_f32(N,Kf)^T ========
template<int MF, int KC, bool HSEL>
DEVFN void gemm_bt_body(int bx, int by, bool zsel,
    const __bf16* __restrict__ A, int Kf,
    const float* __restrict__ B0, float* __restrict__ C0,
    const float* __restrict__ B1, float* __restrict__ C1,
    int N)
{
  constexpr int Mp = 16 * MF;
  const int lane = threadIdx.x & 63, w = threadIdx.x >> 6;
  const int n0 = bx * 64 + w * 16;
  const int k0 = by * KC * 32;
  const float* B = zsel ? B1 : B0;
  float* Cp      = zsel ? C1 : C0;
  const __bf16* aBase = A + (HSEL ? (long)(n0 >> 9) * Mp * Kf : 0)
                          + (long)(lane & 15) * Kf + k0 + 8 * (lane >> 4);
  const float* bBase = B + (long)(n0 + (lane & 15)) * Kf + k0 + 8 * (lane >> 4);
  f32x4 acc[MF];
  #pragma unroll
  for (int m = 0; m < MF; m++) acc[m] = (f32x4)(0.f);
  #pragma unroll 4
  for (int c = 0; c < KC; c++){
    f32x4 lo = *reinterpret_cast<const f32x4*>(bBase + c * 32);
    f32x4 hi = *reinterpret_cast<const f32x4*>(bBase + c * 32 + 4);
    bf16x8 bb = pack8(lo, hi);
    #pragma unroll
    for (int m = 0; m < MF; m++){
      bf16x8 aa = *reinterpret_cast<const bf16x8*>(aBase + (long)m * 16 * Kf + c * 32);
      acc[m] = __builtin_amdgcn_mfma_f32_16x16x32_bf16(aa, bb, acc[m], 0, 0, 0);
    }
  }
  float* cp = Cp + (long)by * Mp * N;
  int row0 = 4 * (lane >> 4), col = n0 + (lane & 15);
  #pragma unroll
  for (int m = 0; m < MF; m++)
    #pragma unroll
    for (int r = 0; r < 4; r++)
      cp[(long)(m * 16 + row0 + r) * N + col] = acc[m][r];
}
template<int MF, int KC, bool HSEL>
__global__ __launch_bounds__(256) void gemm_bt(
    const __bf16* __restrict__ A, int Kf,
    const float* __restrict__ B0, float* __restrict__ C0,
    const float* __restrict__ B1, float* __restrict__ C1, int N)
{
  gemm_bt_body<MF, KC, HSEL>(blockIdx.x, blockIdx.y, blockIdx.z != 0, A, Kf, B0, C0, B1, C1, N);
}

// ======== GEMM-ABNAT: Cp[z][y][Mp][N] = A_bf16(z)(Mp,aStride) @ Bn_f32(z)(K,N) ========
// cBatch MUST equal gridDim.y * Mp * N (z-major slab layout [z][y][Mp][N]).
template<int MF, int KC>
__global__ __launch_bounds__(256) void gemm_abnat(
    const __bf16* __restrict__ A, long aBatch, int aStride,
    const float* __restrict__ Bn, long bBatch,
    float* __restrict__ Cp, long cBatch,
    int N)
{
  constexpr int Mp = 16 * MF;
  const int lane = threadIdx.x & 63, w = threadIdx.x >> 6;
  const int z = blockIdx.z;
  const int n0 = blockIdx.x * 64 + w * 16;
  const int k0 = blockIdx.y * KC * 32;
  const __bf16* aBase = A + z * aBatch + (long)(lane & 15) * aStride + k0 + 8 * (lane >> 4);
  const float* bBase = Bn + z * bBatch + (long)(k0 + 8 * (lane >> 4)) * N + n0 + (lane & 15);
  f32x4 acc[MF];
  #pragma unroll
  for (int m = 0; m < MF; m++) acc[m] = (f32x4)(0.f);
  #pragma unroll 2
  for (int c = 0; c < KC; c++){
    const float* bp = bBase + (long)c * 32 * N;
    bf16x8 bb;
    #pragma unroll
    for (int j = 0; j < 8; j++) bb[j] = (__bf16)bp[(long)j * N];
    #pragma unroll
    for (int m = 0; m < MF; m++){
      bf16x8 aa = *reinterpret_cast<const bf16x8*>(aBase + (long)m * 16 * aStride + c * 32);
      acc[m] = __builtin_amdgcn_mfma_f32_16x16x32_bf16(aa, bb, acc[m], 0, 0, 0);
    }
  }
  float* cp = Cp + z * cBatch + (long)blockIdx.y * Mp * N;
  int row0 = 4 * (lane >> 4), col = n0 + (lane & 15);
  #pragma unroll
  for (int m = 0; m < MF; m++)
    #pragma unroll
    for (int r = 0; r < 4; r++)
      cp[(long)(m * 16 + row0 + r) * N + col] = acc[m][r];
}

// ======== q GEMM with f32 A (queries), row-pad + scale folded in; grid (32,16) KC=4 ========
__global__ __launch_bounds__(256) void gemm_qA(
    const float* __restrict__ queries, const float* __restrict__ Wq, float* __restrict__ Cp)
{
  const int lane = threadIdx.x & 63, w = threadIdx.x >> 6;
  const int n0 = blockIdx.x * 64 + w * 16;
  const int k0 = blockIdx.y * 4 * 32;
  const int r0 = lane & 15, r1 = r0 + 16;
  const float f1 = (r1 < NQQ) ? SCALE_F : 0.f;
  const float* a0 = queries + (long)r0 * HH + k0 + 8 * (lane >> 4);
  const float* a1 = queries + (long)((r1 < NQQ) ? r1 : 0) * HH + k0 + 8 * (lane >> 4);
  const float* bBase = Wq + (long)(n0 + r0) * HH + k0 + 8 * (lane >> 4);
  f32x4 acc[2]; acc[0] = (f32x4)(0.f); acc[1] = (f32x4)(0.f);
  #pragma unroll
  for (int c = 0; c < 4; c++){
    f32x4 blo = *reinterpret_cast<const f32x4*>(bBase + c * 32);
    f32x4 bhi = *reinterpret_cast<const f32x4*>(bBase + c * 32 + 4);
    bf16x8 bb = pack8(blo, bhi);
    f32x4 l0 = *reinterpret_cast<const f32x4*>(a0 + c * 32);
    f32x4 h0 = *reinterpret_cast<const f32x4*>(a0 + c * 32 + 4);
    f32x4 l1 = *reinterpret_cast<const f32x4*>(a1 + c * 32);
    f32x4 h1 = *reinterpret_cast<const f32x4*>(a1 + c * 32 + 4);
    bf16x8 aa0, aa1;
    #pragma unroll
    for (int i = 0; i < 4; i++){
      aa0[i] = (__bf16)(l0[i] * SCALE_F); aa0[i+4] = (__bf16)(h0[i] * SCALE_F);
      aa1[i] = (__bf16)(l1[i] * f1);      aa1[i+4] = (__bf16)(h1[i] * f1);
    }
    acc[0] = __builtin_amdgcn_mfma_f32_16x16x32_bf16(aa0, bb, acc[0], 0, 0, 0);
    acc[1] = __builtin_amdgcn_mfma_f32_16x16x32_bf16(aa1, bb, acc[1], 0, 0, 0);
  }
  float* cp = Cp + (long)blockIdx.y * 32 * HH;
  int row0 = 4 * (lane >> 4), col = n0 + r0;
  #pragma unroll
  for (int m = 0; m < 2; m++)
    #pragma unroll
    for (int r = 0; r < 4; r++)
      cp[(long)(m * 16 + row0 + r) * HH + col] = acc[m][r];
}

// ======== pass1: Sp[y][b][qh][s] = hs(b)(s,H) @ qk_bf16(80,H)^T  (y=4, KC=16) ========
template<int KC>
__global__ __launch_bounds__(256) void gemm_pass1(
    const float* __restrict__ hs, const __bf16* __restrict__ qk,
    float* __restrict__ Sp)
{
  const int lane = threadIdx.x & 63, w = threadIdx.x >> 6;
  const int b = blockIdx.z;
  const int s0 = blockIdx.x * 64 + w * 16;
  const int k0 = blockIdx.y * KC * 32;
  const float* aBase = hs + ((long)b * SS + s0 + (lane & 15)) * HH + k0 + 8 * (lane >> 4);
  const __bf16* bBase = qk + (long)(lane & 15) * HH + k0 + 8 * (lane >> 4);
  f32x4 acc[5];
  #pragma unroll
  for (int n = 0; n < 5; n++) acc[n] = (f32x4)(0.f);
  #pragma unroll 4
  for (int c = 0; c < KC; c++){
    f32x4 lo = *reinterpret_cast<const f32x4*>(aBase + c * 32);
    f32x4 hi = *reinterpret_cast<const f32x4*>(aBase + c * 32 + 4);
    bf16x8 aa = pack8(lo, hi);
    #pragma unroll
    for (int n = 0; n < 5; n++){
      bf16x8 bb = *reinterpret_cast<const bf16x8*>(bBase + (long)n * 16 * HH + c * 32);
      acc[n] = __builtin_amdgcn_mfma_f32_16x16x32_bf16(aa, bb, acc[n], 0, 0, 0);
    }
  }
  float* sp = Sp + ((long)blockIdx.y * 4 + b) * 80 * SS;
  int scol = s0 + 4 * (lane >> 4);
  #pragma unroll
  for (int n = 0; n < 5; n++){
    int qh = n * 16 + (lane & 15);
    *reinterpret_cast<f32x4*>(sp + (long)qh * SS + scol) = acc[n];
  }
}

// ======== merged FFN launches (independent GEMMs by block range, no sync) ========
__global__ __launch_bounds__(256) void k_ffn1(
    const __bf16* __restrict__ xnb, const float* __restrict__ Wgate, const float* __restrict__ Wup,
    float* __restrict__ gate_p, float* __restrict__ up_p,
    const __bf16* __restrict__ vi, const float* __restrict__ V1, float* __restrict__ h1_p)
{
  int bid = blockIdx.x;
  if (bid < 1024){                                   // gate/up: (64,8,2), KC=8, 8 slabs
    int z = bid >> 9, rem = bid & 511;
    gemm_bt_body<4, 8, false>(rem & 63, rem >> 6, z != 0, xnb, 2048, Wgate, gate_p, Wup, up_p, 4096);
  } else {                                           // V1: (32,16), KC=8, 16 slabs
    int t = bid - 1024;
    gemm_bt_body<1, 8, false>(t & 31, t >> 5, false, vi, 4096, V1, h1_p, V1, h1_p, 2048);
  }
}
__global__ __launch_bounds__(256) void k_ffn2(
    const __bf16* __restrict__ hb, const float* __restrict__ Wdown, float* __restrict__ ffn_p,
    const __bf16* __restrict__ h1s, const float* __restrict__ V2, float* __restrict__ h2_p)
{
  int bid = blockIdx.x;
  if (bid < 512){                                    // down: (32,16), KC=8, 16 slabs
    gemm_bt_body<4, 8, false>(bid & 31, bid >> 5, false, hb, 4096, Wdown, ffn_p, Wdown, ffn_p, 2048);
  } else {                                           // V2: (8,16), KC=4, 16 slabs
    int t = bid - 512;
    gemm_bt_body<1, 4, false>(t & 7, t >> 3, false, h1s, 2048, V2, h2_p, V2, h2_p, 512);
  }
}
__global__ void k_act2(const float* __restrict__ gate_p, const float* __restrict__ up_p,
                       __bf16* __restrict__ hb,
                       const float* __restrict__ h1_p, const float* __restrict__ b1,
                       __bf16* __restrict__ h1s)
{
  int bid = blockIdx.x;
  if (bid < 1024){                                   // silu(gate)*up, 8 slabs
    long i = (long)bid * 256 + threadIdx.x;          // 64*4096
    float g = 0.f, u = 0.f;
    #pragma unroll
    for (int y = 0; y < 8; y++){
      g += gate_p[(long)y * 64 * 4096 + i];
      u += up_p[(long)y * 64 * 4096 + i];
    }
    hb[i] = (__bf16)(siluf(g) * u);
  } else {                                           // h1act, 16 slabs
    int i = (bid - 1024) * 256 + threadIdx.x;        // 16*2048
    int r = i >> 11, e = i & 2047;
    float v = 0.f;
    if (r < 4){
      float s = 0.f;
      #pragma unroll
      for (int y = 0; y < 16; y++) s += h1_p[(long)y * 16 * 2048 + i];
      v = siluf(s + b1[e]);
    }
    h1s[i] = (__bf16)v;
  }
}

// ---------------- small / epilogue kernels ----------------
__global__ void k_mkQ2(const float* __restrict__ q_p, __bf16* __restrict__ Q2){
  int i = blockIdx.x * 256 + threadIdx.x;       // 80*2048
  int qh = i >> 11, e = i & 2047;
  float v = 0.f;
  if (qh < QH){
    int h = qh / NQQ, qq = qh - h * NQQ;
    if ((e >> 9) == h){
      float s = 0.f;
      #pragma unroll
      for (int y = 0; y < 16; y++) s += q_p[(long)y * 32 * 2048 + qq * 2048 + e];
      v = s;                                     // scale already folded into gemm_qA
    }
  }
  Q2[i] = (__bf16)v;
}
__global__ void k_mkqk(const float* __restrict__ qk_p, __bf16* __restrict__ qk_bf){
  int i = blockIdx.x * 256 + threadIdx.x;       // 80*2048
  float s = 0.f;
  #pragma unroll
  for (int y = 0; y < 16; y++) s += qk_p[(long)y * 80 * 2048 + i];
  qk_bf[i] = (__bf16)s;
}
__global__ __launch_bounds__(256) void k_softmax(const float* __restrict__ Sp, __bf16* __restrict__ attn){
  int qh = blockIdx.x, b = blockIdx.y;
  __bf16* arow = attn + ((long)b * 80 + qh) * SS;
  if (qh >= QH){
    #pragma unroll
    for (int it = 0; it < 16; it++) arow[threadIdx.x + 256 * it] = (__bf16)0.f;
    return;
  }
  const float* r0 = Sp + ((long)b * 80 + qh) * SS;
  const long ys = (long)4 * 80 * SS;
  float x[16]; float mx = -1e30f;
  #pragma unroll
  for (int it = 0; it < 16; it++){
    int s = threadIdx.x + 256 * it;
    x[it] = (r0[s] + r0[s + ys]) + (r0[s + 2 * ys] + r0[s + 3 * ys]);
    mx = fmaxf(mx, x[it]);
  }
  __shared__ float sb[8];
  #pragma unroll
  for (int o = 32; o > 0; o >>= 1) mx = fmaxf(mx, __shfl_xor(mx, o));
  int wid = threadIdx.x >> 6, lane = threadIdx.x & 63;
  if (lane == 0) sb[wid] = mx;
  __syncthreads();
  mx = fmaxf(fmaxf(sb[0], sb[1]), fmaxf(sb[2], sb[3]));
  float sum = 0.f;
  #pragma unroll
  for (int it = 0; it < 16; it++){ x[it] = expf(x[it] - mx); sum += x[it]; }
  #pragma unroll
  for (int o = 32; o > 0; o >>= 1) sum += __shfl_xor(sum, o);
  if (lane == 0) sb[4 + wid] = sum;
  __syncthreads();
  sum = sb[4] + sb[5] + sb[6] + sb[7];
  float inv = 1.f / sum;
  #pragma unroll
  for (int it = 0; it < 16; it++) arow[threadIdx.x + 256 * it] = (__bf16)(x[it] * inv);
}
// w_p layout [b][y][80][2048], y in [0,8)
__global__ void k_pack_wv(const float* __restrict__ w_p, __bf16* __restrict__ Apack){
  int i = blockIdx.x * 256 + threadIdx.x;       // 4*80*2048
  int h = i / (80 * 2048);
  int r = (i / 2048) % 80;
  int e = i & 2047;
  float v = 0.f;
  if (r < QH){
    int b = r / NQQ, qq = r - b * NQQ;
    const float* base = w_p + ((long)b * 8 * 80 + (h * NQQ + qq)) * 2048 + e;
    #pragma unroll
    for (int y = 0; y < 8; y++) v += base[(long)y * 80 * 2048];
  }
  Apack[i] = (__bf16)v;
}
__global__ void k_sum_outB(const float* __restrict__ outB_p, __bf16* __restrict__ outB){
  int i = blockIdx.x * 256 + threadIdx.x;       // 80*2048
  float s = 0.f;
  #pragma unroll
  for (int y = 0; y < 16; y++) s += outB_p[(long)y * 80 * 2048 + i];
  outB[i] = (__bf16)s;
}
// rms + extracted materialization + vi packing fused. grid 96. (16 ext slabs)
__global__ __launch_bounds__(256) void k_rms(const float* __restrict__ ext_p, const float* __restrict__ ln_w,
                                             const float* __restrict__ hs,
                                             float* __restrict__ extracted, __bf16* __restrict__ xnb,
                                             __bf16* __restrict__ vi){
  int r = blockIdx.x;
  if (r >= 80){
    if (r < 84){                                 // vi[b][2048..4096] = hs[b, S-1, :]
      int b = r - 80;
      const float* src = hs + ((long)b * SS + (SS - 1)) * HH;
      #pragma unroll
      for (int it = 0; it < 8; it++){
        int e = threadIdx.x + 256 * it;
        vi[(long)b * 4096 + 2048 + e] = (__bf16)src[e];
      }
    } else {                                     // zero vi rows 4..15
      int row = 4 + (r - 84);
      #pragma unroll
      for (int it = 0; it < 16; it++)
        vi[(long)row * 4096 + threadIdx.x + 256 * it] = (__bf16)0.f;
    }
    return;
  }
  float xv[8]; float ss = 0.f;
  #pragma unroll
  for (int it = 0; it < 8; it++){
    int e = threadIdx.x + 256 * it;
    float s = 0.f;
    #pragma unroll
    for (int y = 0; y < 16; y++) s += ext_p[((long)y * 80 + r) * 2048 + e];
    extracted[(long)r * 2048 + e] = s;
    xv[it] = s;
    ss += s * s;
  }
  if (r >= QH) return;
  int b = r / NQQ, qq = r - b * NQQ;
  if (qq < 16){
    __shared__ float sb[4];
    ss = block_sum(ss, sb);
    float inv = 1.f / sqrtf(ss * (1.f / 2048.f) + 1e-6f);
    __bf16* dst = xnb + (long)(b * 16 + qq) * HH;
    #pragma unroll
    for (int it = 0; it < 8; it++){
      int e = threadIdx.x + 256 * it;
      dst[e] = (__bf16)(xv[it] * inv * ln_w[e]);
    }
  } else if (qq == 17){                          // vi[b][0..2048] = extracted row
    #pragma unroll
    for (int it = 0; it < 8; it++){
      int e = threadIdx.x + 256 * it;
      vi[(long)b * 4096 + e] = (__bf16)xv[it];
    }
  }
}
// memory + priority + confidence + value, one kernel. grid 72. (16 ffn slabs, 16 h2 slabs)
__global__ __launch_bounds__(256) void k_epilogue(
    const float* __restrict__ extracted, const float* __restrict__ ffn_p,
    const float* __restrict__ h2_p,
    const float* __restrict__ Wp, const float* __restrict__ bp,
    const float* __restrict__ Wh, const float* __restrict__ bh,
    const float* __restrict__ b2, const float* __restrict__ V3, const float* __restrict__ b3,
    float* __restrict__ out)
{
  __shared__ float sb[4];
  int blk = blockIdx.x;
  if (blk < 64){                                 // memory row + priority
    int b = blk >> 4, qq = blk & 15;
    const float* ext = extracted + (long)(b * NQQ + qq) * HH;
    float pv = 0.f;
    #pragma unroll
    for (int it = 0; it < 8; it++){
      int e = threadIdx.x + 256 * it;
      float f = 0.f;
      #pragma unroll
      for (int y = 0; y < 16; y++) f += ffn_p[((long)y * 64 + blk) * 2048 + e];
      float m = ext[e] + f;
      out[OUT_MEM + (long)blk * 2048 + e] = m;
      pv += m * Wp[e];
    }
    pv = block_sum(pv, sb);
    if (threadIdx.x == 0) out[OUT_PRI + blk] = 1.f / (1.f + expf(-(pv + bp[0])));
  } else if (blk < 68){                          // confidence
    int b = blk - 64;
    const float* m = extracted + (long)(b * NQQ + 16) * HH;
    float v = 0.f;
    #pragma unroll
    for (int it = 0; it < 8; it++){ int e = threadIdx.x + 256 * it; v += m[e] * Wh[e]; }
    v = block_sum(v, sb);
    if (threadIdx.x == 0) out[OUT_CONF + b] = 1.f / (1.f + expf(-(v + bh[0])));
  } else {                                       // value
    int b = blk - 68;
    float v = 0.f;
    #pragma unroll
    for (int it = 0; it < 2; it++){
      int j = threadIdx.x + 256 * it;
      float s = 0.f;
      #pragma unroll
      for (int y = 0; y < 16; y++) s += h2_p[(long)y * 16 * 512 + b * 512 + j];
      v += siluf(s + b2[j]) * V3[j];
    }
    v = block_sum(v, sb);
    if (threadIdx.x == 0) out[OUT_VAL + b] = v + b3[0];
  }
}
// block-redundant scan + entry copy (128 blocks)
__global__ void k_scanentries(const float* __restrict__ buf_pri, const float* __restrict__ buf_ent,
                              float* __restrict__ out){
  __shared__ int tws;
  int bid = blockIdx.x, tid = threadIdx.x;
  if (tid < 64){
    int lane = tid;
    float pr0 = buf_pri[lane], pr1 = buf_pri[lane + 64];
    int tw0 = -1, tw1 = -1;
    for (int i = 0; i < 16; i++){
      float pp = out[OUT_PRI + i];
      float v; int idx;
      if (pr0 <= pr1){ v = pr0; idx = lane; } else { v = pr1; idx = lane + 64; }
      #pragma unroll
      for (int o = 32; o > 0; o >>= 1){
        float ov = __shfl_xor(v, o);
        int   oi = __shfl_xor(idx, o);
        if (ov < v || (ov == v && oi < idx)){ v = ov; idx = oi; }
      }
      if (pp > v){
        if (idx == lane)          { pr0 = pp; tw0 = i; }
        else if (idx == lane + 64){ pr1 = pp; tw1 = i; }
      }
    }
    if (bid == 0){
      out[OUT_NEWPRI + lane]      = pr0;
      out[OUT_NEWPRI + lane + 64] = pr1;
    }
    if (lane == (bid & 63)) tws = (bid < 64) ? tw0 : tw1;
  }
  __syncthreads();
  int t = tws;
  const f32x4* s = reinterpret_cast<const f32x4*>(
      (t < 0) ? (buf_ent + (long)bid * HH) : (out + OUT_MEM + (long)t * HH));
  f32x4* d = reinterpret_cast<f32x4*>(out + OUT_ENT + (long)bid * HH);
  #pragma unroll
  for (int i = 0; i < 2; i++) d[tid + 256 * i] = s[tid + 256 * i];
}

// ---------------- launcher ----------------
extern "C" void kernel_launch(void* const* d_in, const int* in_sizes, int n_in,
                              void* d_out, int out_size, void* d_ws, size_t ws_size,
                              hipStream_t stream)
{
  const float* hs      = (const float*)d_in[0];
  const float* buf_ent = (const float*)d_in[1];
  const float* buf_pri = (const float*)d_in[2];
  const float* queries = (const float*)d_in[3];
  const float* Wq  = (const float*)d_in[4];
  const float* Wk  = (const float*)d_in[5];
  const float* Wv  = (const float*)d_in[6];
  const float* Wo  = (const float*)d_in[7];
  const float* ln_w= (const float*)d_in[8];
  const float* Wgate=(const float*)d_in[9];
  const float* Wup = (const float*)d_in[10];
  const float* Wdown=(const float*)d_in[11];
  const float* Wp  = (const float*)d_in[12];
  const float* bp  = (const float*)d_in[13];
  const float* Wh  = (const float*)d_in[14];
  const float* bh  = (const float*)d_in[15];
  const float* V1  = (const float*)d_in[16];
  const float* b1  = (const float*)d_in[17];
  const float* V2  = (const float*)d_in[18];
  const float* b2  = (const float*)d_in[19];
  const float* V3  = (const float*)d_in[20];
  const float* b3  = (const float*)d_in[21];
  float* out = (float*)d_out;
  char* ws = (char*)d_ws;

  // ---- RegionA (time-aliased at ws+0; lifetimes strictly serial) ----
  float* q_p      = (float*)(ws + 0);            // [16][32][2048]
  float* qk_p     = (float*)(ws + 0);            // [16][80][2048]
  float* scores_p = (float*)(ws + 0);            // [4][4][80][4096]
  float* w_p      = (float*)(ws + 0);            // [4][8][80][2048]
  float* outB_p   = (float*)(ws + 0);            // [16][80][2048]
  float* ext_p    = (float*)(ws + 0);            // [16][80][2048]
  float* gate_p   = (float*)(ws + 0);            // [8][64][4096]
  float* up_p     = (float*)(ws + 8388608);      // [8][64][4096]
  float* ffn_p    = (float*)(ws + 0);            // [16][64][2048]
  // ---- persistents (from 20,971,520) ----
  __bf16* Q2    = (__bf16*)(ws + 21102592);      // 80*2048
  __bf16* qk_bf = (__bf16*)(ws + 21430272);      // 80*2048
  __bf16* attn  = (__bf16*)(ws + 21757952);      // 4*80*4096
  __bf16* Apack = (__bf16*)(ws + 24379392);      // 4*80*2048
  __bf16* outB  = (__bf16*)(ws + 25690112);      // 80*2048
  float*  extracted = (float*)(ws + 26017792);   // 80*2048 f32
  __bf16* xnb   = (__bf16*)(ws + 26673152);      // 64*2048
  __bf16* hb    = (__bf16*)(ws + 26935296);      // 64*4096
  __bf16* vi    = (__bf16*)(ws + 27459584);      // 16*4096
  __bf16* h1s   = (__bf16*)(ws + 27590656);      // 16*2048
  float*  h1_p  = (float*)(ws + 27656192);       // [16][16][2048]
  float*  h2_p  = (float*)(ws + 29753344);       // [16][16][512]

  // q = (scale*queries) @ Wq^T  (prep + scale folded into A-load), 16 slabs
  gemm_qA<<<dim3(32, 16), 256, 0, stream>>>(queries, Wq, q_p);
  k_mkQ2<<<640, 256, 0, stream>>>(q_p, Q2);
  // qk = Q2 @ Wk, 16 slabs
  gemm_abnat<5, 4><<<dim3(32, 16, 1), 256, 0, stream>>>(Q2, 0, 2048, Wk, 0, qk_p, 0, 2048);
  k_mkqk<<<640, 256, 0, stream>>>(qk_p, qk_bf);
  // pass1: scores_t[y][b][qh][s] = hs @ qk^T, 4 slabs
  gemm_pass1<16><<<dim3(64, 4, 4), 256, 0, stream>>>(hs, qk_bf, scores_p);
  k_softmax<<<dim3(80, 4), 256, 0, stream>>>(scores_p, attn);
  // pass3: weighted = attn @ hs, 8 slabs; w_p [b][8][80][2048]
  gemm_abnat<5, 16><<<dim3(32, 8, 4), 256, 0, stream>>>(attn, 80L * 4096, 4096,
      hs, (long)SS * HH, w_p, 8L * 80 * 2048, 2048);
  k_pack_wv<<<2560, 256, 0, stream>>>(w_p, Apack);
  // V projection (block-diag by head), 16 slabs
  gemm_bt<5, 4, true><<<dim3(32, 16, 1), 256, 0, stream>>>(Apack, 2048, Wv, outB_p, Wv, outB_p, 2048);
  k_sum_outB<<<640, 256, 0, stream>>>(outB_p, outB);
  // O projection, 16 slabs
  gemm_bt<5, 4, false><<<dim3(32, 16, 1), 256, 0, stream>>>(outB, 2048, Wo, ext_p, Wo, ext_p, 2048);
  k_rms<<<96, 256, 0, stream>>>(ext_p, ln_w, hs, extracted, xnb, vi);
  // FFN up+gate (8 slabs) + value-MLP layer 1 (16 slabs), merged launch
  k_ffn1<<<1536, 256, 0, stream>>>(xnb, Wgate, Wup, gate_p, up_p, vi, V1, h1_p);
  k_act2<<<1152, 256, 0, stream>>>(gate_p, up_p, hb, h1_p, b1, h1s);
  // FFN down (16 slabs) + value-MLP layer 2 (16 slabs), merged launch
  k_ffn2<<<640, 256, 0, stream>>>(hb, Wdown, ffn_p, h1s, V2, h2_p);
  // outputs
  k_epilogue<<<72, 256, 0, stream>>>(extracted, ffn_p, h2_p, Wp, bp, Wh, bh, b2, V3, b3, out);
  k_scanentries<<<128, 256, 0, stream>>>(buf_pri, buf_ent, out);
}